// Round 5
// baseline (54.213 us; speedup 1.0000x reference)
//
#include <hip/hip_runtime.h>

// WiSARD inference: B=4096, ENTRY=1024, TUPLE=16, CLASSES=10, NEURONS=64.
// out[b][c] = sum_n ram_bit[c][n][addr(b,c,n)]
//
//  1. packT : samples -> bitT[1024 bitpos][64 sgroup] u64 (LDS 64x64 transpose)
//  2. fused : block=(cn,half of addr space): build 4096 addrs from bitT
//             (scalar loads + cndmask), mark needed 64B lines in a bitmap,
//             compact to a SORTED line list, fetch only needed lines
//             (~63% of bytes), pack to LDS bit-table, lookup, ballot ->
//             partial[cn][h][64] u64 masks
//  3. reduce: OR halves, ballot-popcount over neurons -> out[4096][10] f32

#define BATCH   4096
#define ENTRY   1024
#define TUPLE   16
#define CLASSES 10
#define NEURONS 64
#define CN      (CLASSES * NEURONS)   // 640
#define ADDRSP  65536
#define HALF    (ADDRSP / 2)          // 32768 cells
#define HLINES  (HALF / 16)           // 2048 64B lines per half

typedef unsigned long long u64;
typedef unsigned int       u32;
typedef unsigned short     u16;

// ---------------- Kernel 1: bit-transpose pack (coalesced) ----------------
__global__ __launch_bounds__(256) void packT_kernel(
    const int* __restrict__ samples, u64* __restrict__ bitT)
{
    __shared__ int tile[64 * 65];
    const int sg   = blockIdx.x >> 4;
    const int cg   = blockIdx.x & 15;
    const int w    = threadIdx.x >> 6;
    const int lane = threadIdx.x & 63;
    const int t    = threadIdx.x;

#pragma unroll
    for (int rnd = 0; rnd < 4; ++rnd) {
        const int idx  = rnd * 256 + t;
        const int row  = idx >> 4;
        const int col4 = idx & 15;
        const int4 v = *reinterpret_cast<const int4*>(
            samples + (size_t)(sg * 64 + row) * ENTRY + cg * 64 + col4 * 4);
        int* tp = tile + row * 65 + col4 * 4;
        tp[0] = v.x; tp[1] = v.y; tp[2] = v.z; tp[3] = v.w;
    }
    __syncthreads();

#pragma unroll
    for (int k = 0; k < 16; ++k) {
        const int j = w * 16 + k;
        const u64 m = __ballot(tile[lane * 65 + j] & 1);
        if (lane == 0) bitT[(size_t)(cg * 64 + j) * 64 + sg] = m;
    }
}

// ---------------- Kernel 2: fused addr + needed-line gather + lookup -----
// grid 1280 blocks x 256 (5 blocks/CU). block -> (cn, half).
__global__ __launch_bounds__(256) void fused_kernel(
    const int* __restrict__ tm, const float* __restrict__ ram,
    const u64* __restrict__ bitT, u64* __restrict__ partial)
{
    __shared__ u16 addrL[BATCH];        // 8 KB: this cn's 4096 addresses
    __shared__ u32 bm[HLINES / 32];     // 256 B: needed-line bitmap (this half)
    __shared__ u16 list[HLINES];        // 4 KB: sorted needed-line list
    __shared__ u16 tbl[HLINES];         // 4 KB: 16 ram bits per needed line
    __shared__ int nT;

    const int bid  = blockIdx.x;
    const int cn   = bid >> 1;
    const int h    = bid & 1;
    const int c    = cn >> 6;
    const int n    = cn & 63;
    const int tid  = threadIdx.x;
    const int lane = tid & 63;
    const int wu   = __builtin_amdgcn_readfirstlane(tid >> 6);

    if (tid < HLINES / 32) bm[tid] = 0u;
    __syncthreads();

    // ---- Phase A: build addresses (scalar bitT loads + cndmask select),
    //      mark needed lines of this half in the bitmap ----
    const int* tp = tm + c * ENTRY + n * TUPLE;   // uniform -> s_load
    int E[TUPLE];
#pragma unroll
    for (int tt = 0; tt < TUPLE; ++tt) E[tt] = tp[tt];

#pragma unroll
    for (int k = 0; k < 16; ++k) {
        const int sg = wu * 16 + k;     // uniform -> bitT via s_load_dwordx2
        u32 a = 0;
#pragma unroll
        for (int tt = 0; tt < TUPLE; ++tt) {
            const u64 word = bitT[(size_t)E[tt] * 64 + sg];
            u32 bit;
            asm("v_cndmask_b32 %0, 0, 1, %1" : "=v"(bit) : "s"(word));
            a = (a << 1) | bit;
        }
        addrL[sg * 64 + lane] = (u16)a;
        if ((a >> 15) == (u32)h) {
            const u32 line = (a & (HALF - 1)) >> 4;     // 0..2047
            atomicOr(&bm[line >> 5], 1u << (line & 31u));
        }
    }
    __syncthreads();

    // ---- Compaction (wave 0): bitmap -> sorted line list ----
    if (wu == 0) {
        u32 word = bm[lane];            // 64 words x 32 bits = 2048 lines
        const int ccnt = __popc(word);
        int x = ccnt;                   // inclusive prefix scan over 64 lanes
#pragma unroll
        for (int i = 1; i < 64; i <<= 1) {
            const int y = __shfl_up(x, i);
            if (lane >= i) x += y;
        }
        int o = x - ccnt;               // exclusive offset
        while (word) {
            const int b2 = __builtin_ctz(word);
            word &= word - 1;
            list[o++] = (u16)(lane * 32 + b2);
        }
        if (lane == 63) nT = x;
    }
    __syncthreads();

    // ---- Phase B: fetch ONLY needed lines (sorted), pack bits into tbl ----
    // quad of lanes per 64B line; lane q loads float4 #q of the line.
    const float4* rp = reinterpret_cast<const float4*>(
        ram + (size_t)cn * ADDRSP + h * HALF);
    const int nLines = nT;
    const int q = tid & 3;
    for (int e = (tid >> 2); e < nLines; e += 64) {
        const int line = list[e];
        const float4 v = rp[line * 4 + q];
        u32 nib = (u32)(v.x != 0.0f) | ((u32)(v.y != 0.0f) << 1) |
                  ((u32)(v.z != 0.0f) << 2) | ((u32)(v.w != 0.0f) << 3);
        u32 x = nib << (q * 4);
        x |= __shfl_xor(x, 1);
        x |= __shfl_xor(x, 2);
        if (q == 0) tbl[line] = (u16)x;
    }
    __syncthreads();

    // ---- Phase C: lookup 4096 addresses ----
    u64* pp = partial + (size_t)cn * 128 + h * 64;
#pragma unroll
    for (int i = 0; i < 16; ++i) {
        const u32 a     = addrL[wu * 1024 + i * 64 + lane];
        const u32 local = a & (HALF - 1);
        const u32 w16   = tbl[local >> 4];
        u32 bit = (w16 >> (a & 15u)) & 1u;
        bit &= (u32)((a >> 15) == (u32)h);
        const u64 m = __ballot(bit != 0u);
        if (lane == 0) pp[wu * 16 + i] = m;
    }
}

// ---------------- Kernel 3: reduce ----------------
__global__ __launch_bounds__(256) void reduce_kernel(
    const u64* __restrict__ partial, float* __restrict__ out)
{
    const int gid  = blockIdx.x * 4 + (threadIdx.x >> 6);  // 0..639
    const int lane = threadIdx.x & 63;
    const int c    = gid >> 6;
    const int sg   = gid & 63;

    const u64* pp = partial + ((size_t)(c * NEURONS + lane)) * 128 + sg;
    const u64 m = pp[0] | pp[64];

    float myv = 0.0f;
#pragma unroll
    for (int b2 = 0; b2 < 64; ++b2) {
        const u64 mb = __ballot((u32)(m >> b2) & 1u);
        if (lane == b2) myv = (float)__popcll(mb);
    }
    out[(sg * 64 + lane) * CLASSES + c] = myv;
}

extern "C" void kernel_launch(void* const* d_in, const int* in_sizes, int n_in,
                              void* d_out, int out_size, void* d_ws, size_t ws_size,
                              hipStream_t stream)
{
    const int*   samples = (const int*)d_in[0];
    const int*   tm      = (const int*)d_in[1];
    const float* ram     = (const float*)d_in[2];
    float*       out     = (float*)d_out;

    u64* bitT    = (u64*)d_ws;                              // 512 KB
    u64* partial = (u64*)((char*)d_ws + (512u << 10));      // 640 KB

    packT_kernel <<<1024, 256, 0, stream>>>(samples, bitT);
    fused_kernel <<<CN * 2, 256, 0, stream>>>(tm, ram, bitT, partial);
    reduce_kernel<<<CN / 4, 256, 0, stream>>>(partial, out);
}